// Round 4
// baseline (320.516 us; speedup 1.0000x reference)
//
#include <hip/hip_runtime.h>

// HBV 2.0 fused scan + gamma-UH routing, MI355X (gfx950). Round 11.
// Evidence so far (VALU-busy-time invariant ~19.5M cy across R7-R10; all
// deltas are stall): R7=170.7 (per-step ds_reads, ring in-chain, WAIT14),
// R8=200/R9=226 (mid-body read placement: exposed DS latency), R10=181.5
// (batched 30-read block: serial read drain + lost overlap; proved per-step
// DS reads in R7 were already hidden). Per-step realized 561 cy for ~87 cy
// VALU issue => ~6.4 cy/instr: schedule is near-fully serialized.
// R11 experiment (T1): the 15-tap ring (17 instr/step, independent of the
// recurrence) is serialized dead weight in the body. Save Qt[15] and run
// the 15x15 UH convolution as a batched chunk epilogue (15 parallel
// accumulation chains, ~2.2 cy/instr). Accumulation order per slot is
// j-ascending in both forms -> bit-identical. Plus: med3/gw-max forms
// (bit-identical, verified R9/R10) and corrected waits on the R7 skeleton
// (14 first / 29 steady / 15 final: fresh stores never force-drained).

#define TS 730
#define NG 10000
#define CH 15
#define NCHUNK 49            // 49*15 = 735 >= 730
#define XSTRIDE (NG * 3)
#define DSTRIDE (NG * 4)

#define AS1 __attribute__((address_space(1)))
#define AS3 __attribute__((address_space(3)))
// gfx9/CDNA s_waitcnt simm16: vmcnt[3:0]=simm[3:0], vmcnt[5:4]=simm[15:14],
// expcnt=simm[6:4], lgkmcnt=simm[11:8]
#define WAIT_VMCNT(n) __builtin_amdgcn_s_waitcnt(((n) & 15) | 0x70 | 0xF00 | (((n) >> 4) << 14))
#define WAIT_LGKM0    __builtin_amdgcn_s_waitcnt(0xC07F)

__device__ __forceinline__ void gload16(const float* g, float* l) {
    __builtin_amdgcn_global_load_lds((const AS1 void*)g, (AS3 void*)l, 16, 0, 0);
}
// x^b for x>0 via native v_log_f32 + v_exp_f32
__device__ __forceinline__ float powpos(float x, float b) {
    return __builtin_amdgcn_exp2f(b * __builtin_amdgcn_logf(x));
}
// clamp(x, lo, hi) for lo<=hi, finite inputs: identical to min(max(x,lo),hi)
__device__ __forceinline__ float med3(float x, float lo, float hi) {
    return __builtin_amdgcn_fmed3f(x, lo, hi);
}

__global__ __launch_bounds__(64, 1) void hbv_fused(
    const float* __restrict__ x_phy,
    const float* __restrict__ ac_all,
    const float* __restrict__ params_dy,
    const float* __restrict__ params_stat,
    float* __restrict__ out)
{
    // LDS double buffers in exact DMA lane order (lane i -> base + i*16B).
    __shared__ float xls0[1536], xls1[1536];
    __shared__ float dls0[2048], dls1[2048];

    const int lane = threadIdx.x & 63;
    const int m    = lane >> 5;            // nmul component
    const int cell = lane & 31;
    const int g0   = blockIdx.x * 32;
    const int g    = g0 + cell;
    const int gl   = g < NG ? g : NG - 1;
    // last block: shift 32-cell window left so staging never reads OOB
    const int g0r  = (g0 <= NG - 32) ? g0 : NG - 32;
    const int co   = cell + (g0 - g0r);
    const int cl   = co < 31 ? co : 31;    // LDS cell slot (stores masked for dups)

    // ---- static params: params_stat[g, i*2 + m]; routing at 28,29 ----
    const float* ps = params_stat + (size_t)gl * 30;
    const float FC    = ps[0  + m] * 950.f   + 50.f;
    const float K0    = ps[2  + m] * 0.85f   + 0.05f;
    const float K1    = ps[4  + m] * 0.49f   + 0.01f;
    const float K2    = ps[6  + m] * 0.199f  + 0.001f;
    const float LP    = ps[8  + m] * 0.8f    + 0.2f;
    const float PERCp = ps[10 + m] * 10.f;
    const float UZL   = ps[12 + m] * 100.f;
    const float TTp   = ps[14 + m] * 5.f     - 2.5f;
    const float CFMAX = ps[16 + m] * 9.5f    + 0.5f;
    const float CFR   = ps[18 + m] * 0.1f;
    const float CWH   = ps[20 + m] * 0.2f;
    const float Cc    = ps[22 + m];
    const float RT    = ps[24 + m] * 20.f;
    const float ACp   = ps[26 + m] * 2500.f;
    const float ra    = ps[28] * 2.9f;
    const float rb    = ps[29] * 6.5f;

    const float Acv     = ac_all[gl];
    const float invFC   = 1.f / FC;
    const float invLPFC = 1.f / (LP * FC);
    const float CFRC    = CFR * CFMAX;
    const float gwcap   = RT * fminf(fmaxf(1.f - Acv / (ACp + 1e-5f), 0.f), 1.f);

    // ---- UH weights (normalization cancels gammaln/theta^-a prefactor) ----
    const float a     = fmaxf(ra, 0.f) + 0.1f;
    const float th    = fmaxf(rb, 0.f) + 0.5f;
    const float am1   = a - 1.f;
    const float nl2e  = 1.44269504f / th;
    float w[CH];
    float wsum = 0.f;
#pragma unroll
    for (int k = 0; k < CH; ++k) {
        const float tk = (float)k + 0.5f;
        const float v  = __builtin_amdgcn_exp2f(am1 * __builtin_amdgcn_logf(tk) - tk * nl2e);
        w[k] = v; wsum += v;
    }
    const float wn = 0.5f / wsum;  // fold nmul-mean 0.5 into weights
#pragma unroll
    for (int k = 0; k < CH; ++k) w[k] *= wn;

    // ---- per-lane DMA source offsets (float units), chunk-relative ----
    int offx[6], offd[8];
#pragma unroll
    for (int i = 0; i < 6; ++i) {
        int idx = i * 64 + lane;
        idx = idx < 360 ? idx : 359;
        const int row = idx / 24;
        const int col = idx - row * 24;
        offx[i] = row * XSTRIDE + col * 4;
    }
#pragma unroll
    for (int i = 0; i < 8; ++i) {
        int idx = i * 64 + lane;
        idx = idx < 480 ? idx : 479;
        const int row = idx >> 5;
        const int col = idx & 31;
        offd[i] = row * DSTRIDE + col * 4;
    }
    const float* xbase = x_phy     + (size_t)g0r * 3;
    const float* dbase = params_dy + (size_t)g0r * 4;

    auto issue = [&](int cc, float* xl, float* dl) {  // exactly 14 DMA ops
        if (cc == NCHUNK - 1) {
            // last chunk: rows 10..14 would hit t=730..734 -> clamp abs t
#pragma unroll
            for (int i = 0; i < 6; ++i) {
                int idx = i * 64 + lane; idx = idx < 360 ? idx : 359;
                const int row = idx / 24, col = idx - row * 24;
                int t = cc * CH + row; t = t < TS ? t : TS - 1;
                gload16(xbase + (size_t)t * XSTRIDE + col * 4, xl + i * 256);
            }
#pragma unroll
            for (int i = 0; i < 8; ++i) {
                int idx = i * 64 + lane; idx = idx < 480 ? idx : 479;
                const int row = idx >> 5, col = idx & 31;
                int t = cc * CH + row; t = t < TS ? t : TS - 1;
                gload16(dbase + (size_t)t * DSTRIDE + col * 4, dl + i * 256);
            }
        } else {
            const float* xp = xbase + (size_t)cc * CH * XSTRIDE;
            const float* dp = dbase + (size_t)cc * CH * DSTRIDE;
#pragma unroll
            for (int i = 0; i < 6; ++i) gload16(xp + offx[i], xl + i * 256);
#pragma unroll
            for (int i = 0; i < 8; ++i) gload16(dp + offd[i], dl + i * 256);
        }
    };

    // ---- state + routing ring (epilogue-only now) ----
    float SP = 1e-3f, MW = 1e-3f, SM = 1e-3f, SUZ = 1e-3f, SLZ = 1e-3f;
    float facc[CH];
#pragma unroll
    for (int k = 0; k < CH; ++k) facc[k] = 0.f;

    const bool doStore = (g < NG) && (lane < 32);

    auto chunk = [&](int c, const float* xl, const float* dl) {
        float qts[CH];
        // R7-style 1-step software pipeline: reads for j+1 issued at the
        // top of step j, consumed next iteration (read-to-use ~ full step).
        float Pc = xl[cl * 3 + 0], Tc = xl[cl * 3 + 1], Ec = xl[cl * 3 + 2];
        float4 dvc = *(const float4*)&dl[cl * 4];
#pragma unroll
        for (int j = 0; j < CH; ++j) {
            float Pn, Tn, En; float4 dvn;
            if (j < CH - 1) {
                Pn  = xl[(j + 1) * 96 + cl * 3 + 0];
                Tn  = xl[(j + 1) * 96 + cl * 3 + 1];
                En  = xl[(j + 1) * 96 + cl * 3 + 2];
                dvn = *(const float4*)&dl[(j + 1) * 128 + cl * 4];
            }
            const float Pt = Pc, Tt = Tc, PETt = Ec;
            const float beta   = (m ? dvc.y : dvc.x) * 5.f  + 1.f;
            const float betaet = (m ? dvc.w : dvc.z) * 4.7f + 0.3f;

            // snow bucket (med3 == min(max(x,0),cap), bit-identical)
            const float rain = (Tt >= TTp) ? Pt : 0.f;
            SP += Pt - rain;
            const float melt = med3(CFMAX * (Tt - TTp), 0.f, SP);
            MW += melt; SP -= melt;
            const float refr = med3(CFRC * (TTp - Tt), 0.f, MW);
            SP += refr; MW -= refr;
            const float tosoil = fmaxf(MW - CWH * SP, 0.f);
            MW -= tosoil;

            // soil bucket (SM > 0 strictly: native log safe)
            const float sw  = fminf(powpos(SM * invFC, beta), 1.f);
            const float rts = rain + tosoil;
            SM = fmaf(rts, 1.f - sw, SM);
            const float exc = fmaxf(SM - FC, 0.f);
            SM = fminf(SM, FC);
            const float ef = powpos(fminf(SM * invLPFC, 1.f), betaet);
            const float ET = fminf(SM, PETt * ef);
            SM = fmaxf(SM - ET, 1e-5f);
            // Cc<=1, factor<=1 -> product <= SLZ; reference min is redundant
            const float cap = Cc * SLZ * (1.f - fminf(SM * invFC, 1.f));
            SM  = fmaxf(SM + cap, 1e-5f);
            SLZ = fmaxf(SLZ - cap, 1e-5f);

            // groundwater buckets
            SUZ += rts * sw + exc;
            const float perc = fminf(SUZ, PERCp);
            SUZ -= perc;
            const float Q0 = K0 * fmaxf(SUZ - UZL, 0.f);
            SUZ -= Q0;
            const float Q1 = K1 * SUZ;
            SUZ -= Q1;
            SLZ += perc;
            SLZ = fmaxf(SLZ - gwcap, 0.f);   // == SLZ - min(SLZ,gwcap), bitwise
            const float Q2 = K2 * SLZ;
            SLZ -= Q2;
            qts[j] = Q0 + Q1 + Q2;           // ring deferred to epilogue

            Pc = Pn; Tc = Tn; Ec = En; dvc = dvn;
        }

        // ---- batched UH convolution epilogue ----
        // Per slot, contributions accumulate in ascending-j order exactly as
        // the per-step ring did -> bit-identical. 15 parallel chains, same-
        // slot writes 15 instructions apart -> runs at issue rate.
        float ofl[CH];
#pragma unroll
        for (int j = 0; j < CH; ++j) {
#pragma unroll
            for (int k = 0; k < CH; ++k)
                facc[(j + k) % CH] = fmaf(w[k], qts[j], facc[(j + k) % CH]);
            ofl[j]  = facc[j];   // own-half partial flow[t] complete
            facc[j] = 0.f;       // recycle slot for t+15
        }

        // batched cross-half combine (15 ds_permute, off the chain)
        float prt[CH];
#pragma unroll
        for (int jj = 0; jj < CH; ++jj) prt[jj] = __shfl_xor(ofl[jj], 32);
        // stores last: at the next chunk's WAIT_VMCNT(29) they are among the
        // 29 newest VM ops (15 stores + 14 fresh loads) -> never drained.
        if (doStore) {
            float* op = out + (size_t)c * CH * NG + g;
            const int tb = c * CH;
#pragma unroll
            for (int jj = 0; jj < CH; ++jj)
                if (tb + jj < TS) op[(size_t)jj * NG] = ofl[jj] + prt[jj];
        }
    };

    // prolog: both buffers' DMAs in flight
    issue(0, xls0, dls0);
    issue(1, xls1, dls1);

    // chunk 0: outstanding = loads(0)+loads(1); drain loads(0) -> WAIT(14)
    WAIT_VMCNT(14);
    chunk(0, xls0, dls0);
    WAIT_LGKM0;                            // ds_reads/permutes retired (WAR)
    issue(2, xls0, dls0);
    // chunk 1: newer than loads(1): stores(0)[15] + loads(2)[14] = 29
    WAIT_VMCNT(29);
    chunk(1, xls1, dls1);
    WAIT_LGKM0;
    issue(3, xls1, dls1);

    // steady state: chunks 2..47 in pairs, two static-buffer instantiations
    for (int cp = 1; cp < 24; ++cp) {
        const int c0 = 2 * cp;
        // newer than loads(c0): stores(c0-1)[15] + loads(c0+1)[14] = 29
        WAIT_VMCNT(29);
        chunk(c0, xls0, dls0);
        WAIT_LGKM0;
        issue(c0 + 2, xls0, dls0);         // up to issue(48)
        WAIT_VMCNT(29);
        chunk(c0 + 1, xls1, dls1);
        WAIT_LGKM0;
        if (cp < 23) issue(c0 + 3, xls1, dls1);  // up to issue(47)
    }
    // newer than loads(48): stores(47)[15] -> WAIT(15)
    WAIT_VMCNT(15);
    chunk(48, xls0, dls0);
}

extern "C" void kernel_launch(void* const* d_in, const int* in_sizes, int n_in,
                              void* d_out, int out_size, void* d_ws, size_t ws_size,
                              hipStream_t stream) {
    const float* x_phy = (const float*)d_in[0];
    const float* ac    = (const float*)d_in[1];
    // d_in[2] = elev_all: unused by the reference forward
    const float* pdy   = (const float*)d_in[3];
    const float* pst   = (const float*)d_in[4];
    float* out = (float*)d_out;

    const int grid = (NG + 31) / 32;  // 313 single-wave blocks
    hbv_fused<<<grid, 64, 0, stream>>>(x_phy, ac, pdy, pst, out);
}

// Round 5
// 276.006 us; speedup vs baseline: 1.1613x; 1.1613x over previous
//
#include <hip/hip_runtime.h>

// HBV 2.0 fused scan + gamma-UH routing, MI355X (gfx950). Round 12.
// R7..R11 ledger: 170/200/226/181/170us; VALU-busy-time invariant ~31.5us
// => all deltas stall; OccupancyPercent calibration (313/8192=3.8%~3.4%)
// shows SQ metrics average over ALL SIMDs => per-wave VALU issue ~60% of
// wall (~340cy/step): the scan wave is ISSUE-heavy. Latency tricks are
// exhausted; the lever is fewer instructions on the critical wave.
// R12: wave specialization. Block = 2 waves.
//   wave0 (critical): pure scan. ds_read inputs (1-step pipelined),
//     recurrence body (micro-golfed, bit-identical forms), 1 ds_write of
//     Qt/step. ZERO VMEM, zero vmcnt waits, no ring/shfl/stores/DMA.
//   wave1 (slack, ~5% duty): all 14 DMA issues/chunk, 15-tap UH conv of
//     Qt (cross-half combine = q0+q1 at input; shfl eliminated), output
//     stores, all vmcnt bookkeeping.
// Handoff: 50 s_barriers (K_0..K_49). wave1 drains loads(n) (per-wave
// vmcnt) before K_n; wave0 reads xls[n&1] after K_n; wave1 issues loads
// into a buffer only after the barrier proving wave0 finished reading it.
// Qt via qb0/qb1 ping-pong; conv(n) runs between K_{n+1} and K_{n+2} while
// wave0 writes the OTHER qb. Golf (bit-identical): shared t1 for melt/refr
// args; ET fuse SM=max(SM-PETt*ef,1e-5) (== min-then-sub form, proven);
// carried CcSLZ (== Cc*SLZ at step start); max(1-u,0) == 1-min(u,1).

#define TS 730
#define NG 10000
#define CH 15
#define NCHUNK 49            // 49*15 = 735 >= 730
#define XSTRIDE (NG * 3)
#define DSTRIDE (NG * 4)

#define AS1 __attribute__((address_space(1)))
#define AS3 __attribute__((address_space(3)))
// gfx9/CDNA s_waitcnt simm16: vmcnt[3:0]=simm[3:0], vmcnt[5:4]=simm[15:14],
// expcnt=simm[6:4], lgkmcnt=simm[11:8]
#define WAIT_VMCNT(n) __builtin_amdgcn_s_waitcnt(((n) & 15) | 0x70 | 0xF00 | (((n) >> 4) << 14))
#define WAIT_LGKM0    __builtin_amdgcn_s_waitcnt(0xC07F)
#define SBAR          __builtin_amdgcn_s_barrier
#define SCHED_FENCE() __builtin_amdgcn_sched_barrier(0)

__device__ __forceinline__ void gload16(const float* g, float* l) {
    __builtin_amdgcn_global_load_lds((const AS1 void*)g, (AS3 void*)l, 16, 0, 0);
}
// x^b for x>0 via native v_log_f32 + v_exp_f32
__device__ __forceinline__ float powpos(float x, float b) {
    return __builtin_amdgcn_exp2f(b * __builtin_amdgcn_logf(x));
}
// clamp(x, lo, hi) for lo<=hi, finite inputs: identical to min(max(x,lo),hi)
__device__ __forceinline__ float med3(float x, float lo, float hi) {
    return __builtin_amdgcn_fmed3f(x, lo, hi);
}

__global__ __launch_bounds__(128, 1) void hbv_fused(
    const float* __restrict__ x_phy,
    const float* __restrict__ ac_all,
    const float* __restrict__ params_dy,
    const float* __restrict__ params_stat,
    float* __restrict__ out)
{
    // LDS: input double buffers in exact DMA lane order + Qt ping-pong.
    __shared__ float xls0[1536], xls1[1536];
    __shared__ float dls0[2048], dls1[2048];
    __shared__ float qb0[960], qb1[960];   // [15][64] Qt per chunk

    const int tid  = threadIdx.x;
    const int wid  = tid >> 6;             // 0 = scan wave, 1 = service wave
    const int lane = tid & 63;
    const int m    = lane >> 5;            // nmul component
    const int cell = lane & 31;
    const int g0   = blockIdx.x * 32;
    const int g    = g0 + cell;
    const int gl   = g < NG ? g : NG - 1;
    // last block: shift 32-cell window left so staging never reads OOB
    const int g0r  = (g0 <= NG - 32) ? g0 : NG - 32;
    const int co   = cell + (g0 - g0r);
    const int cl   = co < 31 ? co : 31;    // LDS cell slot

    // ---- static params: params_stat[g, i*2 + m]; routing at 28,29 ----
    const float* ps = params_stat + (size_t)gl * 30;
    const float FC    = ps[0  + m] * 950.f   + 50.f;
    const float K0    = ps[2  + m] * 0.85f   + 0.05f;
    const float K1    = ps[4  + m] * 0.49f   + 0.01f;
    const float K2    = ps[6  + m] * 0.199f  + 0.001f;
    const float LP    = ps[8  + m] * 0.8f    + 0.2f;
    const float PERCp = ps[10 + m] * 10.f;
    const float UZL   = ps[12 + m] * 100.f;
    const float TTp   = ps[14 + m] * 5.f     - 2.5f;
    const float CFMAX = ps[16 + m] * 9.5f    + 0.5f;
    const float CFR   = ps[18 + m] * 0.1f;
    const float CWH   = ps[20 + m] * 0.2f;
    const float Cc    = ps[22 + m];
    const float RT    = ps[24 + m] * 20.f;
    const float ACp   = ps[26 + m] * 2500.f;
    const float ra    = ps[28] * 2.9f;
    const float rb    = ps[29] * 6.5f;

    const float Acv     = ac_all[gl];
    const float invFC   = 1.f / FC;
    const float invLPFC = 1.f / (LP * FC);
    const float nCFRC   = -(CFR * CFMAX);  // refr arg = CFRC*(TTp-Tt) = nCFRC*t1
    const float gwcap   = RT * fminf(fmaxf(1.f - Acv / (ACp + 1e-5f), 0.f), 1.f);

    // ---- UH weights (normalization cancels gammaln/theta^-a prefactor) ----
    const float a     = fmaxf(ra, 0.f) + 0.1f;
    const float th    = fmaxf(rb, 0.f) + 0.5f;
    const float am1   = a - 1.f;
    const float nl2e  = 1.44269504f / th;
    float w[CH];
    float wsum = 0.f;
#pragma unroll
    for (int k = 0; k < CH; ++k) {
        const float tk = (float)k + 0.5f;
        const float v  = __builtin_amdgcn_exp2f(am1 * __builtin_amdgcn_logf(tk) - tk * nl2e);
        w[k] = v; wsum += v;
    }
    const float wn = 0.5f / wsum;  // fold nmul-mean 0.5 into weights
#pragma unroll
    for (int k = 0; k < CH; ++k) w[k] *= wn;

    // ---- per-lane DMA source offsets (float units), chunk-relative ----
    int offx[6], offd[8];
#pragma unroll
    for (int i = 0; i < 6; ++i) {
        int idx = i * 64 + lane;
        idx = idx < 360 ? idx : 359;
        const int row = idx / 24;
        const int col = idx - row * 24;
        offx[i] = row * XSTRIDE + col * 4;
    }
#pragma unroll
    for (int i = 0; i < 8; ++i) {
        int idx = i * 64 + lane;
        idx = idx < 480 ? idx : 479;
        const int row = idx >> 5;
        const int col = idx & 31;
        offd[i] = row * DSTRIDE + col * 4;
    }
    const float* xbase = x_phy     + (size_t)g0r * 3;
    const float* dbase = params_dy + (size_t)g0r * 4;

    auto issue = [&](int cc, float* xl, float* dl) {  // exactly 14 DMA ops
        if (cc == NCHUNK - 1) {
            // last chunk: rows 10..14 would hit t=730..734 -> clamp abs t
#pragma unroll
            for (int i = 0; i < 6; ++i) {
                int idx = i * 64 + lane; idx = idx < 360 ? idx : 359;
                const int row = idx / 24, col = idx - row * 24;
                int t = cc * CH + row; t = t < TS ? t : TS - 1;
                gload16(xbase + (size_t)t * XSTRIDE + col * 4, xl + i * 256);
            }
#pragma unroll
            for (int i = 0; i < 8; ++i) {
                int idx = i * 64 + lane; idx = idx < 480 ? idx : 479;
                const int row = idx >> 5, col = idx & 31;
                int t = cc * CH + row; t = t < TS ? t : TS - 1;
                gload16(dbase + (size_t)t * DSTRIDE + col * 4, dl + i * 256);
            }
        } else {
            const float* xp = xbase + (size_t)cc * CH * XSTRIDE;
            const float* dp = dbase + (size_t)cc * CH * DSTRIDE;
#pragma unroll
            for (int i = 0; i < 6; ++i) gload16(xp + offx[i], xl + i * 256);
#pragma unroll
            for (int i = 0; i < 8; ++i) gload16(dp + offd[i], dl + i * 256);
        }
    };

    if (wid == 0) {
        // =========== wave 0: pure scan (the critical wave) ===========
        float SP = 1e-3f, MW = 1e-3f, SM = 1e-3f, SUZ = 1e-3f, SLZ = 1e-3f;
        float CcSLZ = Cc * 1e-3f;          // == Cc*SLZ at step start, carried

        auto scan = [&](const float* xl, const float* dl, float* qb) {
            // 1-step software pipeline: reads for j+1 at top of step j
            float Pc = xl[cl * 3 + 0], Tc = xl[cl * 3 + 1], Ec = xl[cl * 3 + 2];
            float4 dvc = *(const float4*)&dl[cl * 4];
#pragma unroll
            for (int j = 0; j < CH; ++j) {
                float Pn, Tn, En; float4 dvn;
                if (j < CH - 1) {
                    Pn  = xl[(j + 1) * 96 + cl * 3 + 0];
                    Tn  = xl[(j + 1) * 96 + cl * 3 + 1];
                    En  = xl[(j + 1) * 96 + cl * 3 + 2];
                    dvn = *(const float4*)&dl[(j + 1) * 128 + cl * 4];
                }
                const float beta   = fmaf(m ? dvc.y : dvc.x, 5.f, 1.f);
                const float betaet = fmaf(m ? dvc.w : dvc.z, 4.7f, 0.3f);

                // snow bucket (t1 shared; med3 forms bit-identical)
                const float t1   = Tc - TTp;
                const float snow = (t1 < 0.f) ? Pc : 0.f;   // Tt < TTp
                const float rain = Pc - snow;
                SP += snow;
                const float melt = med3(CFMAX * t1, 0.f, SP);
                MW += melt; SP -= melt;
                const float refr = med3(nCFRC * t1, 0.f, MW);
                SP += refr; MW -= refr;
                const float tosoil = fmaxf(MW - CWH * SP, 0.f);
                MW -= tosoil;

                // soil bucket
                const float sw  = fminf(powpos(SM * invFC, beta), 1.f);
                const float rts = rain + tosoil;
                SM = fmaf(rts, 1.f - sw, SM);
                const float exc = fmaxf(SM - FC, 0.f);
                SM = fminf(SM, FC);
                const float ef = powpos(fminf(SM * invLPFC, 1.f), betaet);
                // ET fuse: == max(SM - min(SM, PETt*ef), 1e-5), proven identical
                SM = fmaxf(SM - Ec * ef, 1e-5f);
                // carried CcSLZ == Cc*SLZ (value at step start); max-form == 1-min
                const float cap = CcSLZ * fmaxf(1.f - SM * invFC, 0.f);
                SM  = fmaxf(SM + cap, 1e-5f);
                SLZ = fmaxf(SLZ - cap, 1e-5f);

                // groundwater buckets
                SUZ = SUZ + rts * sw + exc;
                const float perc = fminf(SUZ, PERCp);
                SUZ -= perc;
                const float Q0 = K0 * fmaxf(SUZ - UZL, 0.f);
                SUZ -= Q0;
                const float Q1 = K1 * SUZ;
                SUZ -= Q1;
                SLZ += perc;
                SLZ = fmaxf(SLZ - gwcap, 0.f);   // == SLZ - min(SLZ,gwcap)
                const float Q2 = K2 * SLZ;
                SLZ -= Q2;
                CcSLZ = Cc * SLZ;                // for next step's capillary
                qb[(j << 6) + lane] = Q0 + Q1 + Q2;  // 1 ds_write, off-chain

                Pc = Pn; Tc = Tn; Ec = En; dvc = dvn;
            }
        };

        SBAR();                                  // K_0 (loads(0) ready)
        scan(xls0, dls0, qb0);                   // chunk 0
        WAIT_LGKM0; SCHED_FENCE();
        for (int cp = 0; cp < 24; ++cp) {
            SBAR();                              // K_{2cp+1}
            scan(xls1, dls1, qb1);               // chunk 2cp+1
            WAIT_LGKM0; SCHED_FENCE();
            SBAR();                              // K_{2cp+2}
            scan(xls0, dls0, qb0);               // chunk 2cp+2 (up to 48)
            WAIT_LGKM0; SCHED_FENCE();
        }
        SBAR();                                  // K_49
    } else {
        // ====== wave 1: DMA engine + UH conv + stores (slack wave) ======
        float facc[CH];
#pragma unroll
        for (int k = 0; k < CH; ++k) facc[k] = 0.f;
        const bool doStore = (g < NG) && (lane < 32);
        const int  l32 = lane & 31;

        auto conv = [&](int c, const float* qb) {
            float* op = out + (size_t)c * CH * NG + g;
            const int tb = c * CH;
#pragma unroll
            for (int j = 0; j < CH; ++j) {
                // cross-half combine at input (0.5 folded into w)
                const float qm = qb[(j << 6) + l32] + qb[(j << 6) + 32 + l32];
#pragma unroll
                for (int k = 0; k < CH; ++k)
                    facc[(j + k) % CH] = fmaf(w[k], qm, facc[(j + k) % CH]);
                if (doStore && (tb + j < TS)) op[(size_t)j * NG] = facc[j];
                facc[j] = 0.f;               // recycle slot for t+15
            }
        };

        issue(0, xls0, dls0);
        WAIT_VMCNT(0); SCHED_FENCE();
        SBAR();                                  // K_0
        issue(1, xls1, dls1);
        WAIT_VMCNT(0); SCHED_FENCE();
        SBAR();                                  // K_1
        for (int cp = 0; cp < 24; ++cp) {
            // between K_{2cp+1} and K_{2cp+2}:
            // xls0 free (wave0 read chunk 2cp before K_{2cp+1});
            // qb0 holds Qt(2cp), complete since K_{2cp+1}.
            issue(2 * cp + 2, xls0, dls0);       // loads(2cp+2), cp=23 -> 48
            conv(2 * cp, qb0);                   // + stores, newest vm ops
            WAIT_VMCNT(15); SCHED_FENCE();       // drain loads, keep stores
            SBAR();                              // K_{2cp+2}
            if (cp < 23) issue(2 * cp + 3, xls1, dls1);
            conv(2 * cp + 1, qb1);
            WAIT_VMCNT(15); SCHED_FENCE();
            SBAR();                              // K_{2cp+3}
        }
        conv(48, qb0);                           // after K_49; wave0 may exit
    }
}

extern "C" void kernel_launch(void* const* d_in, const int* in_sizes, int n_in,
                              void* d_out, int out_size, void* d_ws, size_t ws_size,
                              hipStream_t stream) {
    const float* x_phy = (const float*)d_in[0];
    const float* ac    = (const float*)d_in[1];
    // d_in[2] = elev_all: unused by the reference forward
    const float* pdy   = (const float*)d_in[3];
    const float* pst   = (const float*)d_in[4];
    float* out = (float*)d_out;

    const int grid = (NG + 31) / 32;  // 313 blocks x (scan wave + service wave)
    hbv_fused<<<grid, 128, 0, stream>>>(x_phy, ac, pdy, pst, out);
}

// Round 6
// 270.835 us; speedup vs baseline: 1.1834x; 1.0191x over previous
//
#include <hip/hip_runtime.h>

// HBV 2.0 fused scan + gamma-UH routing, MI355X (gfx950). Round 13.
// R12 (wave specialization) = 123.6us dispatch (406 cy/step), confirming
// wall = issue+stall of the single scan wave. Remaining stall ~230cy/step
// is serial-chain latency; the chain holds TWO pow (log+exp) latencies.
// R13: sw-pow off the chain. sw(j) = f(SM_end(j-1), beta(j)) only ->
// compute swn right after SM finalizes in step j (post-cap), using dvn
// read at the TOP of step j (~35 instr lead; R9's failure was reading dvn
// 3 instr before use). swn's trans latency hides under the groundwater +
// next snow chain. Step j+1 then starts with sw in a register; only ef's
// pow remains on the chain. Chunk-top: one on-chain pow (1/15 amortized).
// All values bit-identical to R12 -> absmax unchanged. Rider: setprio(1)
// on the scan wave (arbitration where 2 blocks share a CU).

#define TS 730
#define NG 10000
#define CH 15
#define NCHUNK 49            // 49*15 = 735 >= 730
#define XSTRIDE (NG * 3)
#define DSTRIDE (NG * 4)

#define AS1 __attribute__((address_space(1)))
#define AS3 __attribute__((address_space(3)))
// gfx9/CDNA s_waitcnt simm16: vmcnt[3:0]=simm[3:0], vmcnt[5:4]=simm[15:14],
// expcnt=simm[6:4], lgkmcnt=simm[11:8]
#define WAIT_VMCNT(n) __builtin_amdgcn_s_waitcnt(((n) & 15) | 0x70 | 0xF00 | (((n) >> 4) << 14))
#define WAIT_LGKM0    __builtin_amdgcn_s_waitcnt(0xC07F)
#define SBAR          __builtin_amdgcn_s_barrier
#define SCHED_FENCE() __builtin_amdgcn_sched_barrier(0)

__device__ __forceinline__ void gload16(const float* g, float* l) {
    __builtin_amdgcn_global_load_lds((const AS1 void*)g, (AS3 void*)l, 16, 0, 0);
}
// x^b for x>0 via native v_log_f32 + v_exp_f32
__device__ __forceinline__ float powpos(float x, float b) {
    return __builtin_amdgcn_exp2f(b * __builtin_amdgcn_logf(x));
}
// clamp(x, lo, hi) for lo<=hi, finite inputs: identical to min(max(x,lo),hi)
__device__ __forceinline__ float med3(float x, float lo, float hi) {
    return __builtin_amdgcn_fmed3f(x, lo, hi);
}

__global__ __launch_bounds__(128, 1) void hbv_fused(
    const float* __restrict__ x_phy,
    const float* __restrict__ ac_all,
    const float* __restrict__ params_dy,
    const float* __restrict__ params_stat,
    float* __restrict__ out)
{
    // LDS: input double buffers in exact DMA lane order + Qt ping-pong.
    __shared__ float xls0[1536], xls1[1536];
    __shared__ float dls0[2048], dls1[2048];
    __shared__ float qb0[960], qb1[960];   // [15][64] Qt per chunk

    const int tid  = threadIdx.x;
    const int wid  = tid >> 6;             // 0 = scan wave, 1 = service wave
    const int lane = tid & 63;
    const int m    = lane >> 5;            // nmul component
    const int cell = lane & 31;
    const int g0   = blockIdx.x * 32;
    const int g    = g0 + cell;
    const int gl   = g < NG ? g : NG - 1;
    // last block: shift 32-cell window left so staging never reads OOB
    const int g0r  = (g0 <= NG - 32) ? g0 : NG - 32;
    const int co   = cell + (g0 - g0r);
    const int cl   = co < 31 ? co : 31;    // LDS cell slot

    // ---- static params: params_stat[g, i*2 + m]; routing at 28,29 ----
    const float* ps = params_stat + (size_t)gl * 30;
    const float FC    = ps[0  + m] * 950.f   + 50.f;
    const float K0    = ps[2  + m] * 0.85f   + 0.05f;
    const float K1    = ps[4  + m] * 0.49f   + 0.01f;
    const float K2    = ps[6  + m] * 0.199f  + 0.001f;
    const float LP    = ps[8  + m] * 0.8f    + 0.2f;
    const float PERCp = ps[10 + m] * 10.f;
    const float UZL   = ps[12 + m] * 100.f;
    const float TTp   = ps[14 + m] * 5.f     - 2.5f;
    const float CFMAX = ps[16 + m] * 9.5f    + 0.5f;
    const float CFR   = ps[18 + m] * 0.1f;
    const float CWH   = ps[20 + m] * 0.2f;
    const float Cc    = ps[22 + m];
    const float RT    = ps[24 + m] * 20.f;
    const float ACp   = ps[26 + m] * 2500.f;
    const float ra    = ps[28] * 2.9f;
    const float rb    = ps[29] * 6.5f;

    const float Acv     = ac_all[gl];
    const float invFC   = 1.f / FC;
    const float invLPFC = 1.f / (LP * FC);
    const float nCFRC   = -(CFR * CFMAX);  // refr arg = CFRC*(TTp-Tt) = nCFRC*t1
    const float gwcap   = RT * fminf(fmaxf(1.f - Acv / (ACp + 1e-5f), 0.f), 1.f);

    // ---- UH weights (normalization cancels gammaln/theta^-a prefactor) ----
    const float a     = fmaxf(ra, 0.f) + 0.1f;
    const float th    = fmaxf(rb, 0.f) + 0.5f;
    const float am1   = a - 1.f;
    const float nl2e  = 1.44269504f / th;
    float w[CH];
    float wsum = 0.f;
#pragma unroll
    for (int k = 0; k < CH; ++k) {
        const float tk = (float)k + 0.5f;
        const float v  = __builtin_amdgcn_exp2f(am1 * __builtin_amdgcn_logf(tk) - tk * nl2e);
        w[k] = v; wsum += v;
    }
    const float wn = 0.5f / wsum;  // fold nmul-mean 0.5 into weights
#pragma unroll
    for (int k = 0; k < CH; ++k) w[k] *= wn;

    // ---- per-lane DMA source offsets (float units), chunk-relative ----
    int offx[6], offd[8];
#pragma unroll
    for (int i = 0; i < 6; ++i) {
        int idx = i * 64 + lane;
        idx = idx < 360 ? idx : 359;
        const int row = idx / 24;
        const int col = idx - row * 24;
        offx[i] = row * XSTRIDE + col * 4;
    }
#pragma unroll
    for (int i = 0; i < 8; ++i) {
        int idx = i * 64 + lane;
        idx = idx < 480 ? idx : 479;
        const int row = idx >> 5;
        const int col = idx & 31;
        offd[i] = row * DSTRIDE + col * 4;
    }
    const float* xbase = x_phy     + (size_t)g0r * 3;
    const float* dbase = params_dy + (size_t)g0r * 4;

    auto issue = [&](int cc, float* xl, float* dl) {  // exactly 14 DMA ops
        if (cc == NCHUNK - 1) {
            // last chunk: rows 10..14 would hit t=730..734 -> clamp abs t
#pragma unroll
            for (int i = 0; i < 6; ++i) {
                int idx = i * 64 + lane; idx = idx < 360 ? idx : 359;
                const int row = idx / 24, col = idx - row * 24;
                int t = cc * CH + row; t = t < TS ? t : TS - 1;
                gload16(xbase + (size_t)t * XSTRIDE + col * 4, xl + i * 256);
            }
#pragma unroll
            for (int i = 0; i < 8; ++i) {
                int idx = i * 64 + lane; idx = idx < 480 ? idx : 479;
                const int row = idx >> 5, col = idx & 31;
                int t = cc * CH + row; t = t < TS ? t : TS - 1;
                gload16(dbase + (size_t)t * DSTRIDE + col * 4, dl + i * 256);
            }
        } else {
            const float* xp = xbase + (size_t)cc * CH * XSTRIDE;
            const float* dp = dbase + (size_t)cc * CH * DSTRIDE;
#pragma unroll
            for (int i = 0; i < 6; ++i) gload16(xp + offx[i], xl + i * 256);
#pragma unroll
            for (int i = 0; i < 8; ++i) gload16(dp + offd[i], dl + i * 256);
        }
    };

    if (wid == 0) {
        // =========== wave 0: pure scan (the critical wave) ===========
        __builtin_amdgcn_s_setprio(1);     // favor the critical wave
        float SP = 1e-3f, MW = 1e-3f, SM = 1e-3f, SUZ = 1e-3f, SLZ = 1e-3f;
        float CcSLZ = Cc * 1e-3f;          // == Cc*SLZ at step start, carried

        auto scan = [&](const float* xl, const float* dl, float* qb) {
            // step-0 inputs + chunk-top sw (one on-chain pow per chunk)
            float Pc = xl[cl * 3 + 0], Tc = xl[cl * 3 + 1], Ec = xl[cl * 3 + 2];
            const float4 dvc = *(const float4*)&dl[cl * 4];
            float swc     = fminf(powpos(SM * invFC,
                                         fmaf(m ? dvc.y : dvc.x, 5.f, 1.f)), 1.f);
            float betaetc = fmaf(m ? dvc.w : dvc.z, 4.7f, 0.3f);
#pragma unroll
            for (int j = 0; j < CH; ++j) {
                // next-step inputs read at STEP TOP (~35 instr lead before
                // any consumer, incl. the late swn precompute -> no exposed
                // DS latency; this was R9's mistake)
                float Pn, Tn, En; float4 dvn;
                if (j < CH - 1) {
                    Pn  = xl[(j + 1) * 96 + cl * 3 + 0];
                    Tn  = xl[(j + 1) * 96 + cl * 3 + 1];
                    En  = xl[(j + 1) * 96 + cl * 3 + 2];
                    dvn = *(const float4*)&dl[(j + 1) * 128 + cl * 4];
                }

                // snow bucket (t1 shared; med3 forms bit-identical)
                const float t1   = Tc - TTp;
                const float snow = (t1 < 0.f) ? Pc : 0.f;   // Tt < TTp
                const float rain = Pc - snow;
                SP += snow;
                const float melt = med3(CFMAX * t1, 0.f, SP);
                MW += melt; SP -= melt;
                const float refr = med3(nCFRC * t1, 0.f, MW);
                SP += refr; MW -= refr;
                const float tosoil = fmaxf(MW - CWH * SP, 0.f);
                MW -= tosoil;

                // soil bucket: swc PRECOMPUTED (last step / chunk top) ->
                // only ef's pow remains on the serial chain
                const float rts = rain + tosoil;
                SM = fmaf(rts, 1.f - swc, SM);
                const float exc = fmaxf(SM - FC, 0.f);
                SM = fminf(SM, FC);
                const float ef = powpos(fminf(SM * invLPFC, 1.f), betaetc);
                // ET fuse: == max(SM - min(SM, PETt*ef), 1e-5), proven identical
                SM = fmaxf(SM - Ec * ef, 1e-5f);
                // carried CcSLZ == Cc*SLZ at step start; max-form == 1-min
                const float cap = CcSLZ * fmaxf(1.f - SM * invFC, 0.f);
                SM  = fmaxf(SM + cap, 1e-5f);
                SLZ = fmaxf(SLZ - cap, 1e-5f);

                // ---- next-step sw precompute (SM is final here). Issues
                // before the groundwater chain; its trans latency hides
                // under ~25 instructions of independent issue. ----
                float swn = 0.f, betaetn = 0.f;
                if (j < CH - 1) {
                    swn = fminf(powpos(SM * invFC,
                                       fmaf(m ? dvn.y : dvn.x, 5.f, 1.f)), 1.f);
                    betaetn = fmaf(m ? dvn.w : dvn.z, 4.7f, 0.3f);
                }

                // groundwater buckets (uses current swc; independent of swn)
                SUZ = SUZ + rts * swc + exc;
                const float perc = fminf(SUZ, PERCp);
                SUZ -= perc;
                const float Q0 = K0 * fmaxf(SUZ - UZL, 0.f);
                SUZ -= Q0;
                const float Q1 = K1 * SUZ;
                SUZ -= Q1;
                SLZ += perc;
                SLZ = fmaxf(SLZ - gwcap, 0.f);   // == SLZ - min(SLZ,gwcap)
                const float Q2 = K2 * SLZ;
                SLZ -= Q2;
                CcSLZ = Cc * SLZ;                // for next step's capillary
                qb[(j << 6) + lane] = Q0 + Q1 + Q2;  // 1 ds_write, off-chain

                Pc = Pn; Tc = Tn; Ec = En;
                swc = swn; betaetc = betaetn;
            }
        };

        SBAR();                                  // K_0 (loads(0) ready)
        scan(xls0, dls0, qb0);                   // chunk 0
        WAIT_LGKM0; SCHED_FENCE();
        for (int cp = 0; cp < 24; ++cp) {
            SBAR();                              // K_{2cp+1}
            scan(xls1, dls1, qb1);               // chunk 2cp+1
            WAIT_LGKM0; SCHED_FENCE();
            SBAR();                              // K_{2cp+2}
            scan(xls0, dls0, qb0);               // chunk 2cp+2 (up to 48)
            WAIT_LGKM0; SCHED_FENCE();
        }
        SBAR();                                  // K_49
    } else {
        // ====== wave 1: DMA engine + UH conv + stores (slack wave) ======
        float facc[CH];
#pragma unroll
        for (int k = 0; k < CH; ++k) facc[k] = 0.f;
        const bool doStore = (g < NG) && (lane < 32);
        const int  l32 = lane & 31;

        auto conv = [&](int c, const float* qb) {
            float* op = out + (size_t)c * CH * NG + g;
            const int tb = c * CH;
#pragma unroll
            for (int j = 0; j < CH; ++j) {
                // cross-half combine at input (0.5 folded into w)
                const float qm = qb[(j << 6) + l32] + qb[(j << 6) + 32 + l32];
#pragma unroll
                for (int k = 0; k < CH; ++k)
                    facc[(j + k) % CH] = fmaf(w[k], qm, facc[(j + k) % CH]);
                if (doStore && (tb + j < TS)) op[(size_t)j * NG] = facc[j];
                facc[j] = 0.f;               // recycle slot for t+15
            }
        };

        issue(0, xls0, dls0);
        WAIT_VMCNT(0); SCHED_FENCE();
        SBAR();                                  // K_0
        issue(1, xls1, dls1);
        WAIT_VMCNT(0); SCHED_FENCE();
        SBAR();                                  // K_1
        for (int cp = 0; cp < 24; ++cp) {
            // between K_{2cp+1} and K_{2cp+2}:
            // xls0 free (wave0 read chunk 2cp before K_{2cp+1});
            // qb0 holds Qt(2cp), complete since K_{2cp+1}.
            issue(2 * cp + 2, xls0, dls0);       // loads(2cp+2), cp=23 -> 48
            conv(2 * cp, qb0);                   // + stores, newest vm ops
            WAIT_VMCNT(15); SCHED_FENCE();       // drain loads, keep stores
            SBAR();                              // K_{2cp+2}
            if (cp < 23) issue(2 * cp + 3, xls1, dls1);
            conv(2 * cp + 1, qb1);
            WAIT_VMCNT(15); SCHED_FENCE();
            SBAR();                              // K_{2cp+3}
        }
        conv(48, qb0);                           // after K_49; wave0 may exit
    }
}

extern "C" void kernel_launch(void* const* d_in, const int* in_sizes, int n_in,
                              void* d_out, int out_size, void* d_ws, size_t ws_size,
                              hipStream_t stream) {
    const float* x_phy = (const float*)d_in[0];
    const float* ac    = (const float*)d_in[1];
    // d_in[2] = elev_all: unused by the reference forward
    const float* pdy   = (const float*)d_in[3];
    const float* pst   = (const float*)d_in[4];
    float* out = (float*)d_out;

    const int grid = (NG + 31) / 32;  // 313 blocks x (scan wave + service wave)
    hbv_fused<<<grid, 128, 0, stream>>>(x_phy, ac, pdy, pst, out);
}

// Round 7
// 258.737 us; speedup vs baseline: 1.2388x; 1.0468x over previous
//
#include <hip/hip_runtime.h>

// HBV 2.0 fused scan + gamma-UH routing, MI355X (gfx950). Round 14.
// R12 (2-wave specialization) = 123.6us. R13 (sw-pow textual move +
// setprio) = 150us REGRESSION: sw(j+1)=f(SM_end(j)) is a TRUE chain link,
// moving it can't shorten the chain; it only perturbed R12's schedule.
// R12 calibration: scan wave issues ~71% of wall (~290 of 406 cy/step) ->
// ISSUE-bound. Lever: fewer instructions on the critical wave.
// R14: split the scan. Snow bucket (SP/MW) never reads soil state back ->
// one-way dataflow via rts=rain+tosoil. 3 waves/block:
//   wave0 snow:   chunk c in [B_c,B_{c+1}): P,T reads, SP/MW chain,
//                 writes rts[15] to rb[c%2].
//   wave1 soil+gw (critical): chunk c in [B_{c+1},B_{c+2}): E,dv,rts
//                 reads, SM/SUZ/SLZ chain (sw-pow + ef-pow + cap),
//                 writes Qt[15] to qb[c%2]. ~55 instr/step (was ~85).
//   wave2 service: DMA (mod-4 input buffers, 2-chunk flight), UH conv of
//                 chunk c in [B_{c+2},B_{c+3}) from qb[c%2], stores,
//                 counted vmcnt (fresh stores never drained).
// 51 barriers B_0..B_50. Buffer lifetimes verified:
//   input buf c%4: DMA [B_{c-2},B_c), snow [B_c,B_{c+1}), soil
//     [B_{c+1},B_{c+2}), next DMA (c+4) issued after B_{c+2}. OK.
//   rb[c%2]: snow writes [B_c,B_{c+1}), soil reads [B_{c+1},B_{c+2}),
//     next write (c+2) [B_{c+2},B_{c+3}). OK.
//   qb[c%2]: soil writes [B_{c+1},B_{c+2}), conv reads [B_{c+2},B_{c+3}),
//     next write (c+2) [B_{c+3},B_{c+4}). OK.
// All per-value arithmetic textually identical to R12 -> bit-identical.

#define TS 730
#define NG 10000
#define CH 15
#define NCHUNK 49            // 49*15 = 735 >= 730
#define XSTRIDE (NG * 3)
#define DSTRIDE (NG * 4)

#define AS1 __attribute__((address_space(1)))
#define AS3 __attribute__((address_space(3)))
// gfx9/CDNA s_waitcnt simm16: vmcnt[3:0]=simm[3:0], vmcnt[5:4]=simm[15:14],
// expcnt=simm[6:4], lgkmcnt=simm[11:8]
#define WAIT_VMCNT(n) __builtin_amdgcn_s_waitcnt(((n) & 15) | 0x70 | 0xF00 | (((n) >> 4) << 14))
#define WAIT_LGKM0    __builtin_amdgcn_s_waitcnt(0xC07F)
#define SBAR          __builtin_amdgcn_s_barrier
#define SCHED_FENCE() __builtin_amdgcn_sched_barrier(0)

__device__ __forceinline__ void gload16(const float* g, float* l) {
    __builtin_amdgcn_global_load_lds((const AS1 void*)g, (AS3 void*)l, 16, 0, 0);
}
// x^b for x>0 via native v_log_f32 + v_exp_f32
__device__ __forceinline__ float powpos(float x, float b) {
    return __builtin_amdgcn_exp2f(b * __builtin_amdgcn_logf(x));
}
// clamp(x, lo, hi) for lo<=hi, finite inputs: identical to min(max(x,lo),hi)
__device__ __forceinline__ float med3(float x, float lo, float hi) {
    return __builtin_amdgcn_fmed3f(x, lo, hi);
}

__global__ __launch_bounds__(192, 1) void hbv_fused(
    const float* __restrict__ x_phy,
    const float* __restrict__ ac_all,
    const float* __restrict__ params_dy,
    const float* __restrict__ params_stat,
    float* __restrict__ out)
{
    // LDS: mod-4 input buffers (DMA lane order) + rts/Qt mod-2 rings.
    __shared__ float xls0[1536], xls1[1536], xls2[1536], xls3[1536];
    __shared__ float dls0[2048], dls1[2048], dls2[2048], dls3[2048];
    __shared__ float rb0[960], rb1[960];   // [15][64] rts per chunk
    __shared__ float qb0[960], qb1[960];   // [15][64] Qt  per chunk

    const int tid  = threadIdx.x;
    const int wid  = tid >> 6;             // 0=snow, 1=soil+gw, 2=service
    const int lane = tid & 63;
    const int m    = lane >> 5;            // nmul component
    const int cell = lane & 31;
    const int g0   = blockIdx.x * 32;
    const int g    = g0 + cell;
    const int gl   = g < NG ? g : NG - 1;
    // last block: shift 32-cell window left so staging never reads OOB
    const int g0r  = (g0 <= NG - 32) ? g0 : NG - 32;
    const int co   = cell + (g0 - g0r);
    const int cl   = co < 31 ? co : 31;    // LDS cell slot

    // ---- static params: params_stat[g, i*2 + m]; routing at 28,29 ----
    const float* ps = params_stat + (size_t)gl * 30;
    const float FC    = ps[0  + m] * 950.f   + 50.f;
    const float K0    = ps[2  + m] * 0.85f   + 0.05f;
    const float K1    = ps[4  + m] * 0.49f   + 0.01f;
    const float K2    = ps[6  + m] * 0.199f  + 0.001f;
    const float LP    = ps[8  + m] * 0.8f    + 0.2f;
    const float PERCp = ps[10 + m] * 10.f;
    const float UZL   = ps[12 + m] * 100.f;
    const float TTp   = ps[14 + m] * 5.f     - 2.5f;
    const float CFMAX = ps[16 + m] * 9.5f    + 0.5f;
    const float CFR   = ps[18 + m] * 0.1f;
    const float CWH   = ps[20 + m] * 0.2f;
    const float Cc    = ps[22 + m];
    const float RT    = ps[24 + m] * 20.f;
    const float ACp   = ps[26 + m] * 2500.f;

    const float Acv     = ac_all[gl];
    const float invFC   = 1.f / FC;
    const float invLPFC = 1.f / (LP * FC);
    const float nCFRC   = -(CFR * CFMAX);  // refr arg = CFRC*(TTp-Tt) = nCFRC*t1
    const float gwcap   = RT * fminf(fmaxf(1.f - Acv / (ACp + 1e-5f), 0.f), 1.f);

    if (wid == 0) {
        // ================= wave 0: snow bucket =================
        float SP = 1e-3f, MW = 1e-3f;
        auto snowc = [&](const float* xl, float* rbuf) {
            float Pc = xl[cl * 3 + 0], Tc = xl[cl * 3 + 1];
#pragma unroll
            for (int j = 0; j < CH; ++j) {
                float Pn, Tn;
                if (j < CH - 1) {
                    Pn = xl[(j + 1) * 96 + cl * 3 + 0];
                    Tn = xl[(j + 1) * 96 + cl * 3 + 1];
                }
                const float t1   = Tc - TTp;
                const float snow = (t1 < 0.f) ? Pc : 0.f;   // Tt < TTp
                const float rain = Pc - snow;
                SP += snow;
                const float melt = med3(CFMAX * t1, 0.f, SP);
                MW += melt; SP -= melt;
                const float refr = med3(nCFRC * t1, 0.f, MW);
                SP += refr; MW -= refr;
                const float tosoil = fmaxf(MW - CWH * SP, 0.f);
                MW -= tosoil;
                rbuf[(j << 6) + lane] = rain + tosoil;       // rts
                Pc = Pn; Tc = Tn;
            }
        };
        SBAR();                                              // B_0
        for (int cq = 0; cq < 12; ++cq) {                    // c = 0..47
            snowc(xls0, rb0); WAIT_LGKM0; SCHED_FENCE(); SBAR();
            snowc(xls1, rb1); WAIT_LGKM0; SCHED_FENCE(); SBAR();
            snowc(xls2, rb0); WAIT_LGKM0; SCHED_FENCE(); SBAR();
            snowc(xls3, rb1); WAIT_LGKM0; SCHED_FENCE(); SBAR();
        }
        snowc(xls0, rb0); WAIT_LGKM0; SCHED_FENCE(); SBAR(); // c=48, B_49
        SBAR();                                              // B_50
    } else if (wid == 1) {
        // ============ wave 1: soil + groundwater (critical) ============
        float SM = 1e-3f, SUZ = 1e-3f, SLZ = 1e-3f;
        float CcSLZ = Cc * 1e-3f;          // == Cc*SLZ at step start, carried
        auto soilc = [&](const float* xl, const float* dl,
                         const float* rbuf, float* qbuf) {
            float Ec   = xl[cl * 3 + 2];
            float4 dvc = *(const float4*)&dl[cl * 4];
            float rtsc = rbuf[lane];
#pragma unroll
            for (int j = 0; j < CH; ++j) {
                float En, rtsn; float4 dvn;
                if (j < CH - 1) {
                    En   = xl[(j + 1) * 96 + cl * 3 + 2];
                    dvn  = *(const float4*)&dl[(j + 1) * 128 + cl * 4];
                    rtsn = rbuf[((j + 1) << 6) + lane];
                }
                const float beta   = fmaf(m ? dvc.y : dvc.x, 5.f, 1.f);
                const float betaet = fmaf(m ? dvc.w : dvc.z, 4.7f, 0.3f);

                // soil bucket (identical ops/order to R12)
                const float sw  = fminf(powpos(SM * invFC, beta), 1.f);
                const float rts = rtsc;
                SM = fmaf(rts, 1.f - sw, SM);
                const float exc = fmaxf(SM - FC, 0.f);
                SM = fminf(SM, FC);
                const float ef = powpos(fminf(SM * invLPFC, 1.f), betaet);
                SM = fmaxf(SM - Ec * ef, 1e-5f);       // ET fuse, proven
                const float cap = CcSLZ * fmaxf(1.f - SM * invFC, 0.f);
                SM  = fmaxf(SM + cap, 1e-5f);
                SLZ = fmaxf(SLZ - cap, 1e-5f);

                // groundwater buckets
                SUZ = SUZ + rts * sw + exc;
                const float perc = fminf(SUZ, PERCp);
                SUZ -= perc;
                const float Q0 = K0 * fmaxf(SUZ - UZL, 0.f);
                SUZ -= Q0;
                const float Q1 = K1 * SUZ;
                SUZ -= Q1;
                SLZ += perc;
                SLZ = fmaxf(SLZ - gwcap, 0.f);         // == SLZ-min(SLZ,gwcap)
                const float Q2 = K2 * SLZ;
                SLZ -= Q2;
                CcSLZ = Cc * SLZ;
                qbuf[(j << 6) + lane] = Q0 + Q1 + Q2;

                Ec = En; dvc = dvn; rtsc = rtsn;
            }
        };
        SBAR();                                              // B_0
        SBAR();                                              // B_1
        for (int cq = 0; cq < 12; ++cq) {                    // c = 0..47
            soilc(xls0, dls0, rb0, qb0); WAIT_LGKM0; SCHED_FENCE(); SBAR();
            soilc(xls1, dls1, rb1, qb1); WAIT_LGKM0; SCHED_FENCE(); SBAR();
            soilc(xls2, dls2, rb0, qb0); WAIT_LGKM0; SCHED_FENCE(); SBAR();
            soilc(xls3, dls3, rb1, qb1); WAIT_LGKM0; SCHED_FENCE(); SBAR();
        }
        soilc(xls0, dls0, rb0, qb0); WAIT_LGKM0; SCHED_FENCE(); SBAR(); // c=48, B_50
    } else {
        // ====== wave 2: DMA engine + UH conv + stores (slack wave) ======
        const float ra = ps[28] * 2.9f;
        const float rb = ps[29] * 6.5f;
        const float a    = fmaxf(ra, 0.f) + 0.1f;
        const float th   = fmaxf(rb, 0.f) + 0.5f;
        const float am1  = a - 1.f;
        const float nl2e = 1.44269504f / th;
        float w[CH];
        float wsum = 0.f;
#pragma unroll
        for (int k = 0; k < CH; ++k) {
            const float tk = (float)k + 0.5f;
            const float v  = __builtin_amdgcn_exp2f(am1 * __builtin_amdgcn_logf(tk) - tk * nl2e);
            w[k] = v; wsum += v;
        }
        const float wn = 0.5f / wsum;  // fold nmul-mean 0.5 into weights
#pragma unroll
        for (int k = 0; k < CH; ++k) w[k] *= wn;

        int offx[6], offd[8];
#pragma unroll
        for (int i = 0; i < 6; ++i) {
            int idx = i * 64 + lane;
            idx = idx < 360 ? idx : 359;
            const int row = idx / 24;
            const int col = idx - row * 24;
            offx[i] = row * XSTRIDE + col * 4;
        }
#pragma unroll
        for (int i = 0; i < 8; ++i) {
            int idx = i * 64 + lane;
            idx = idx < 480 ? idx : 479;
            const int row = idx >> 5;
            const int col = idx & 31;
            offd[i] = row * DSTRIDE + col * 4;
        }
        const float* xbase = x_phy     + (size_t)g0r * 3;
        const float* dbase = params_dy + (size_t)g0r * 4;

        auto issue = [&](int cc, float* xl, float* dl) {  // 14 DMA ops
            if (cc == NCHUNK - 1) {
                // last chunk: rows 10..14 hit t=730..734 -> clamp abs t
#pragma unroll
                for (int i = 0; i < 6; ++i) {
                    int idx = i * 64 + lane; idx = idx < 360 ? idx : 359;
                    const int row = idx / 24, col = idx - row * 24;
                    int t = cc * CH + row; t = t < TS ? t : TS - 1;
                    gload16(xbase + (size_t)t * XSTRIDE + col * 4, xl + i * 256);
                }
#pragma unroll
                for (int i = 0; i < 8; ++i) {
                    int idx = i * 64 + lane; idx = idx < 480 ? idx : 479;
                    const int row = idx >> 5, col = idx & 31;
                    int t = cc * CH + row; t = t < TS ? t : TS - 1;
                    gload16(dbase + (size_t)t * DSTRIDE + col * 4, dl + i * 256);
                }
            } else {
                const float* xp = xbase + (size_t)cc * CH * XSTRIDE;
                const float* dp = dbase + (size_t)cc * CH * DSTRIDE;
#pragma unroll
                for (int i = 0; i < 6; ++i) gload16(xp + offx[i], xl + i * 256);
#pragma unroll
                for (int i = 0; i < 8; ++i) gload16(dp + offd[i], dl + i * 256);
            }
        };

        float facc[CH];
#pragma unroll
        for (int k = 0; k < CH; ++k) facc[k] = 0.f;
        const bool doStore = (g < NG);
        const int  l32 = cell;

        auto conv = [&](int c, const float* qb) {
            float* op = out + (size_t)c * CH * NG + g;
            const int tb = c * CH;
#pragma unroll
            for (int j = 0; j < CH; ++j) {
                // cross-half combine at input (0.5 folded into w)
                const float qm = qb[(j << 6) + l32] + qb[(j << 6) + 32 + l32];
#pragma unroll
                for (int k = 0; k < CH; ++k)
                    facc[(j + k) % CH] = fmaf(w[k], qm, facc[(j + k) % CH]);
                if (doStore && (lane < 32) && (tb + j < TS))
                    op[(size_t)j * NG] = facc[j];
                facc[j] = 0.f;               // recycle slot for t+15
            }
        };

        // prolog
        issue(0, xls0, dls0);
        issue(1, xls1, dls1);
        WAIT_VMCNT(14); SCHED_FENCE(); SBAR();               // B_0
        issue(2, xls2, dls2);
        WAIT_VMCNT(14); SCHED_FENCE(); SBAR();               // B_1
        issue(3, xls3, dls3);
        WAIT_VMCNT(14); SCHED_FENCE(); SBAR();               // B_2
        issue(4, xls0, dls0); conv(0, qb0);
        WAIT_VMCNT(29); SCHED_FENCE(); SBAR();               // B_3
        // steady: intervals n = 3..46 (11 x 4, statically unrolled buffers)
        // at each wait, newest outstanding = stores(n-2)[15] + loads(n+2)[14]
        // + stores(n-3)[<=15] = 44; drains loads(n+1), never a fresh store.
        for (int np = 0; np < 11; ++np) {
            const int n = 3 + 4 * np;
            issue(n + 2, xls1, dls1); conv(n - 2, qb1);
            WAIT_VMCNT(44); SCHED_FENCE(); SBAR();
            issue(n + 3, xls2, dls2); conv(n - 1, qb0);
            WAIT_VMCNT(44); SCHED_FENCE(); SBAR();
            issue(n + 4, xls3, dls3); conv(n,     qb1);
            WAIT_VMCNT(44); SCHED_FENCE(); SBAR();
            issue(n + 5, xls0, dls0); conv(n + 1, qb0);
            WAIT_VMCNT(44); SCHED_FENCE(); SBAR();
        }                                                    // ...B_47
        conv(45, qb1);
        WAIT_VMCNT(30); SCHED_FENCE(); SBAR();               // B_48 (loads(48) drained)
        conv(46, qb0); SBAR();                               // B_49
        conv(47, qb1); SBAR();                               // B_50
        conv(48, qb0);                                       // after B_50
    }
}

extern "C" void kernel_launch(void* const* d_in, const int* in_sizes, int n_in,
                              void* d_out, int out_size, void* d_ws, size_t ws_size,
                              hipStream_t stream) {
    const float* x_phy = (const float*)d_in[0];
    const float* ac    = (const float*)d_in[1];
    // d_in[2] = elev_all: unused by the reference forward
    const float* pdy   = (const float*)d_in[3];
    const float* pst   = (const float*)d_in[4];
    float* out = (float*)d_out;

    const int grid = (NG + 31) / 32;  // 313 blocks x 3 waves
    hbv_fused<<<grid, 192, 0, stream>>>(x_phy, ac, pdy, pst, out);
}